// Round 2
// baseline (178.048 us; speedup 1.0000x reference)
//
#include <hip/hip_runtime.h>
#include <math.h>

#define CEXP 2.8853900817779268f  // 2*log2(e): tanh(z) = 1 - 2/(2^(c*z)+1)
#define TABN 2048   // s(theta) table cells
#define NC   320    // w(x) grid cells per axis
#define NN   321    // w(x) grid nodes per axis
#define WBLK ((NN * NN + 255) / 256)   // 403 blocks for the w-grid

// Tables (rewritten by prep_kernel on every launch; kernel boundary makes
// them visible to interior_kernel across XCDs).
// g_ctab[node] = {w0+y*w4, w1+y*w5, w2+y*w6, w3+y*w7} with y = yita(|node-imv|)
// folded in at prep time -> 16 B/node instead of 32 B. 1.65 MB, L2-resident
// per XCD. Fold error ~ (h^2/8)*|y''*w| ~ 1e-5 at h=1/320 -- negligible.
__device__ float4 g_ctab[NN * NN];
__device__ float2 g_stab2[TABN];        // cell i: {s(p_i), s(p_{i+1}) - s(p_i)}

// tanh with the 2*log2(e) factor pre-folded into the incoming accumulator.
static __device__ __forceinline__ float tanh_pre(float z) {
    float e = __builtin_amdgcn_exp2f(z);
    float r = __builtin_amdgcn_rcpf(e + 1.0f);
    return fmaf(-2.0f, r, 1.0f);
}

// Full phi-branch value s(theta(p)) at diamond-angle parameter p in [-2,2].
static __device__ float s_of_p(float pth,
    const float* __restrict__ Wp1, const float* __restrict__ bp1,
    const float* __restrict__ Wp2, const float* __restrict__ bp2,
    const float* __restrict__ Wp3, const float* __restrict__ bp3,
    const float* __restrict__ Wp4, const float* __restrict__ bp4)
{
    float th;
    if (pth >= -1.0f && pth <= 1.0f) {
        th = atanf(pth / (1.0f - fabsf(pth)));      // /0 -> inf -> atan=pi/2 ok
    } else if (pth > 1.0f) {
        const float uu = 2.0f - pth;                // [0,1)
        th = (float)M_PI - atanf(uu / (1.0f - uu));
    } else {
        const float uu = -2.0f - pth;               // (-1,0]
        th = -(float)M_PI + atanf(-uu / (1.0f + uu));
    }
    const float cth = cosf(th), sth = sinf(th);

    // phi-MLP in f32, tanh via exp2+rcp (matches w-MLP path, ~1e-7 accurate):
    // 2 -> 15 -> 15 -> 15 -> 4
    float h[15], h2[15];
    #pragma unroll
    for (int j = 0; j < 15; ++j)
        h[j] = tanh_pre(CEXP * (cth * Wp1[j] + sth * Wp1[15 + j] + bp1[j]));
    #pragma unroll
    for (int j = 0; j < 15; ++j) {
        float a = bp2[j];
        #pragma unroll
        for (int k = 0; k < 15; ++k) a += h[k] * Wp2[k * 15 + j];
        h2[j] = tanh_pre(CEXP * a);
    }
    #pragma unroll
    for (int j = 0; j < 15; ++j) {
        float a = bp3[j];
        #pragma unroll
        for (int k = 0; k < 15; ++k) a += h2[k] * Wp3[k * 15 + j];
        h[j] = tanh_pre(CEXP * a);
    }
    float ph[4];
    #pragma unroll
    for (int j = 0; j < 4; ++j) {
        float a = bp4[j];
        #pragma unroll
        for (int k = 0; k < 15; ++k) a += h[k] * Wp4[k * 4 + j];
        ph[j] = a;
    }
    return ph[0] + ph[1] * sinf(0.5f * th) + ph[2] * sth + ph[3] * sinf(1.5f * th);
}

// Blocks [0, WBLK): w(x)-grid nodes, weights staged in LDS. Blocks
// [WBLK, WBLK+8): s(theta) table. Branch is BLOCK-uniform.
// __launch_bounds__(256, 2): grid (403 blocks) caps occupancy at ~2 blocks/CU
// anyway, so allow up to 256 VGPRs -- registers are free currency here and the
// extra depth lets the compiler keep more LDS weight-loads in flight (round-1
// counters: VALUBusy 19%, VGPR 100 -> latency-bound on the ds_read->fma chain).
__global__ __launch_bounds__(256, 2) void prep_kernel(
    const float* __restrict__ imv,
    const float* __restrict__ Ww1, const float* __restrict__ bw1,
    const float* __restrict__ Ww2, const float* __restrict__ bw2,
    const float* __restrict__ Ww3, const float* __restrict__ bw3,
    const float* __restrict__ Ww4, const float* __restrict__ bw4,
    const float* __restrict__ Wp1, const float* __restrict__ bp1,
    const float* __restrict__ Wp2, const float* __restrict__ bp2,
    const float* __restrict__ Wp3, const float* __restrict__ bp3,
    const float* __restrict__ Wp4, const float* __restrict__ bp4)
{
    const int t = threadIdx.x;

    if (blockIdx.x < WBLK) {
        // ---- stage prescaled weights into LDS (broadcast-read thereafter) ----
        __shared__ float sW1[60], sb1[30], sW2[900], sb2[30],
                         sW3[900], sb3[30], sW4[240], sb4[8];
        for (int i = t; i < 900; i += 256) {
            sW2[i] = CEXP * Ww2[i];
            sW3[i] = CEXP * Ww3[i];
        }
        for (int i = t; i < 240; i += 256) sW4[i] = Ww4[i];
        if (t < 60) sW1[t] = CEXP * Ww1[t];
        if (t < 30) {
            sb1[t] = CEXP * bw1[t];
            sb2[t] = CEXP * bw2[t];
            sb3[t] = CEXP * bw3[t];
        }
        if (t < 8) sb4[t] = bw4[t];
        __syncthreads();

        const int gid = blockIdx.x * 256 + t;
        if (gid >= NN * NN) return;
        const int ix = gid % NN, iy = gid / NN;
        const float x0 = (float)ix * (1.0f / (float)NC);
        const float x1 = (float)iy * (1.0f / (float)NC);

        float h[30], a[30];
        #pragma unroll
        for (int j = 0; j < 30; ++j)
            h[j] = tanh_pre(fmaf(x1, sW1[30 + j], fmaf(x0, sW1[j], sb1[j])));

        // layer 2: 30 -> 30 (j-inner, float2 LDS reads)
        #pragma unroll
        for (int j = 0; j < 30; ++j) a[j] = sb2[j];
        #pragma unroll
        for (int k = 0; k < 30; ++k) {
            const float hk = h[k];
            #pragma unroll
            for (int jj = 0; jj < 15; ++jj) {
                const float2 w = *(const float2*)&sW2[k * 30 + 2 * jj];
                a[2 * jj]     = fmaf(hk, w.x, a[2 * jj]);
                a[2 * jj + 1] = fmaf(hk, w.y, a[2 * jj + 1]);
            }
        }
        #pragma unroll
        for (int j = 0; j < 30; ++j) a[j] = tanh_pre(a[j]);

        // layer 3: 30 -> 30
        #pragma unroll
        for (int j = 0; j < 30; ++j) h[j] = sb3[j];
        #pragma unroll
        for (int k = 0; k < 30; ++k) {
            const float ak = a[k];
            #pragma unroll
            for (int jj = 0; jj < 15; ++jj) {
                const float2 w = *(const float2*)&sW3[k * 30 + 2 * jj];
                h[2 * jj]     = fmaf(ak, w.x, h[2 * jj]);
                h[2 * jj + 1] = fmaf(ak, w.y, h[2 * jj + 1]);
            }
        }
        #pragma unroll
        for (int j = 0; j < 30; ++j) h[j] = tanh_pre(h[j]);

        // layer 4: 30 -> 8 (unscaled)
        float o[8];
        #pragma unroll
        for (int j = 0; j < 8; ++j) o[j] = sb4[j];
        #pragma unroll
        for (int k = 0; k < 30; ++k) {
            const float hk = h[k];
            #pragma unroll
            for (int jj = 0; jj < 4; ++jj) {
                const float2 w = *(const float2*)&sW4[k * 8 + 2 * jj];
                o[2 * jj]     = fmaf(hk, w.x, o[2 * jj]);
                o[2 * jj + 1] = fmaf(hk, w.y, o[2 * jj + 1]);
            }
        }

        // ---- fold yita(node) into the 8 outputs -> 4 coeffs (16 B/node) ----
        const float ddx = x0 - imv[0], ddy = x1 - imv[1];
        const float rr  = sqrtf(fmaf(ddx, ddx, ddy * ddy));
        const float tt  = fminf(fmaxf(fmaf(2.5f, rr, -1.25f), 0.0f), 1.0f);
        const float tt3 = tt * tt * tt;
        const float yv  = fmaf(fmaf(fmaf(-6.0f, tt, 15.0f), tt, -10.0f), tt3, 1.0f);

        float4 v;
        v.x = fmaf(yv, o[4], o[0]);
        v.y = fmaf(yv, o[5], o[1]);
        v.z = fmaf(yv, o[6], o[2]);
        v.w = fmaf(yv, o[7], o[3]);
        g_ctab[gid] = v;
        return;
    }

    // ---- s(theta) table blocks ----
    const int cell = (blockIdx.x - WBLK) * 256 + t;
    if (cell < TABN) {
        const float hh = 4.0f / (float)TABN;
        const float p0 = -2.0f + hh * (float)cell;
        const float s0 = s_of_p(p0,      Wp1, bp1, Wp2, bp2, Wp3, bp3, Wp4, bp4);
        const float s1 = s_of_p(p0 + hh, Wp1, bp1, Wp2, bp2, Wp3, bp3, Wp4, bp4);
        float2 e; e.x = s0; e.y = s1 - s0;
        g_stab2[cell] = e;
    }
}

// 2 points per thread. Per point: one bilinear gather of the 4 folded coeffs
// (4x dwordx4), one 8 B s(theta) gather, ~70 VALU ops of closed-form geometry.
__global__ __launch_bounds__(256) void interior_kernel(
    const float4* __restrict__ x,      // two points per float4
    const float*  __restrict__ imv,
    const float*  __restrict__ lmbd,
    float* __restrict__ out, int n2)   // n2 = n/2
{
    const int idx = blockIdx.x * blockDim.x + threadIdx.x;
    if (idx >= n2) return;

    const float4 xx = x[idx];
    const float X0[2] = {xx.x, xx.z};
    const float X1[2] = {xx.y, xx.w};
    const float im0 = imv[0], im1 = imv[1], lam = lmbd[0];

    const float4* __restrict__ T = g_ctab;

    float res[2];
    #pragma unroll
    for (int p = 0; p < 2; ++p) {
        const float x0 = X0[p], x1 = X1[p];

        // ---- bilinear gather of folded coeffs c[0..4) from the 2-D grid ----
        const float fx = x0 * (float)NC;
        const float fy = x1 * (float)NC;
        int ix = (int)fx; ix = ix < 0 ? 0 : (ix > NC - 1 ? NC - 1 : ix);
        int iy = (int)fy; iy = iy < 0 ? 0 : (iy > NC - 1 ? NC - 1 : iy);
        const float frx = fx - (float)ix;
        const float fry = fy - (float)iy;

        const int k = iy * NN + ix;              // float4 units
        const float4 A = T[k],      B = T[k + 1];        // (ix,iy) (ix+1,iy)
        const float4 Cq = T[k + NN], D = T[k + NN + 1];  // row iy+1

        float cv[4];
        {
            const float r0x = fmaf(frx, B.x - A.x, A.x);
            const float r0y = fmaf(frx, B.y - A.y, A.y);
            const float r0z = fmaf(frx, B.z - A.z, A.z);
            const float r0w = fmaf(frx, B.w - A.w, A.w);
            const float r1x = fmaf(frx, D.x - Cq.x, Cq.x);
            const float r1y = fmaf(frx, D.y - Cq.y, Cq.y);
            const float r1z = fmaf(frx, D.z - Cq.z, Cq.z);
            const float r1w = fmaf(frx, D.w - Cq.w, Cq.w);
            cv[0] = fmaf(fry, r1x - r0x, r0x);
            cv[1] = fmaf(fry, r1y - r0y, r0y);
            cv[2] = fmaf(fry, r1z - r0z, r0z);
            cv[3] = fmaf(fry, r1w - r0w, r0w);
        }

        // ---- geometry about the interior vertex ----
        const float dx = x0 - im0, dy = x1 - im1;
        const float r  = sqrtf(fmaf(dx, dx, dy * dy));

        // yita(r) -- exact, still needed for the sp term
        const float t  = fminf(fmaxf(fmaf(2.5f, r, -1.25f), 0.0f), 1.0f);
        const float t3 = t * t * t;
        const float yv = fmaf(fmaf(fmaf(-6.0f, t, 15.0f), t, -10.0f), t3, 1.0f);

        // r^lambda (sqrt fast path for lambda == 0.5)
        float rl;
        if (lam == 0.5f) rl = sqrtf(r);
        else rl = __builtin_amdgcn_exp2f(lam * __builtin_amdgcn_logf(fmaxf(r, 1e-20f)));

        // diamond-angle parameter p(theta) in [-2,2], no trig
        const float l1n = fmaxf(fabsf(dx) + fabsf(dy), 1e-20f);
        const float u   = dy * __builtin_amdgcn_rcpf(l1n);
        const float pbk = (dy >= 0.0f) ? (2.0f - u) : (-2.0f - u);
        const float pth = (dx >= 0.0f) ? u : pbk;

        // s(theta) table gather: cell {s, ds}, one 8 B load
        const float fi = fminf(fmaxf(fmaf(pth, (float)(TABN / 4), (float)(TABN / 2)),
                                     0.0f), (float)TABN - 0.001f);
        const int   ii = (int)fi;
        const float fr = fi - (float)ii;
        const float2 sd = g_stab2[ii];
        const float sval = fmaf(fr, sd.y, sd.x);

        // singular functions at x (about origin), algebraically reduced:
        // vp0 = r0^0.5 sin(th/2) = copysign(sqrt((r0-x0)/2), x1)
        // vp1 = x1
        // vp2 = r0^1.5 sin(1.5 th) = x1*sqrt((r0+x0)/2) + x0*vp0
        const float r0 = sqrtf(fmaf(x0, x0, x1 * x1));
        const float Aq = sqrtf(fmaxf(0.0f, (r0 - x0) * 0.5f));
        const float Bq = sqrtf(fmaxf(0.0f, (r0 + x0) * 0.5f));
        const float vp0 = copysignf(Aq, x1);
        const float vp2 = fmaf(x1, Bq, x0 * vp0);

        // combine (yita already folded into cv[])
        float rp = cv[0];
        rp = fmaf(cv[1], vp0, rp);
        rp = fmaf(cv[2], x1, rp);
        rp = fmaf(cv[3], vp2, rp);
        res[p] = fmaf(sval * yv, rl, rp);
    }

    float2 o; o.x = res[0]; o.y = res[1];
    ((float2*)out)[idx] = o;
}

extern "C" void kernel_launch(void* const* d_in, const int* in_sizes, int n_in,
                              void* d_out, int out_size, void* d_ws, size_t ws_size,
                              hipStream_t stream) {
    const float4* x   = (const float4*)d_in[0];
    const float* imv  = (const float*)d_in[1];
    const float* lmbd = (const float*)d_in[2];
    const float* Ww1  = (const float*)d_in[3];
    const float* bw1  = (const float*)d_in[4];
    const float* Ww2  = (const float*)d_in[5];
    const float* bw2  = (const float*)d_in[6];
    const float* Ww3  = (const float*)d_in[7];
    const float* bw3  = (const float*)d_in[8];
    const float* Ww4  = (const float*)d_in[9];
    const float* bw4  = (const float*)d_in[10];
    const float* Wp1  = (const float*)d_in[11];
    const float* bp1  = (const float*)d_in[12];
    const float* Wp2  = (const float*)d_in[13];
    const float* bp2  = (const float*)d_in[14];
    const float* Wp3  = (const float*)d_in[15];
    const float* bp3  = (const float*)d_in[16];
    const float* Wp4  = (const float*)d_in[17];
    const float* bp4  = (const float*)d_in[18];
    float* out = (float*)d_out;

    const int n  = in_sizes[0] / 2;
    const int n2 = n / 2;

    // WBLK blocks for the w-grid + 8 blocks for the s-table.
    prep_kernel<<<WBLK + (TABN + 255) / 256, 256, 0, stream>>>(
        imv,
        Ww1, bw1, Ww2, bw2, Ww3, bw3, Ww4, bw4,
        Wp1, bp1, Wp2, bp2, Wp3, bp3, Wp4, bp4);

    const int block = 256;
    const int grid = (n2 + block - 1) / block;
    interior_kernel<<<grid, block, 0, stream>>>(x, imv, lmbd, out, n2);
}

// Round 3
// 146.943 us; speedup vs baseline: 1.2117x; 1.2117x over previous
//
#include <hip/hip_runtime.h>
#include <math.h>

#define CEXP 2.8853900817779268f  // 2*log2(e): tanh(z) = 1 - 2/(2^(c*z)+1)
#define TABN 2048   // s(theta) table cells
#define NC   320    // w(x) grid cells per axis
#define NN   321    // w(x) grid nodes per axis
#define NNODES (NN * NN)                       // 103041
#define WBLK2 ((NNODES * 2 + 255) / 256)       // 806 blocks, 2 lanes per node

// Tables (rewritten by prep_kernel on every launch; kernel boundary makes
// them visible to interior_kernel across XCDs).
// g_ctab[node] = {w0+y*w4, w1+y*w5, w2+y*w6, w3+y*w7} with y = yita(|node-imv|)
// folded at prep time -> 16 B/node. 1.65 MB, L2-resident.
__device__ float4 g_ctab[NNODES];
__device__ float2 g_stab2[TABN];        // cell i: {s(p_i), s(p_{i+1}) - s(p_i)}

// tanh with the 2*log2(e) factor pre-folded into the incoming accumulator.
static __device__ __forceinline__ float tanh_pre(float z) {
    float e = __builtin_amdgcn_exp2f(z);
    float r = __builtin_amdgcn_rcpf(e + 1.0f);
    return fmaf(-2.0f, r, 1.0f);
}

// Full phi-branch value s(theta(p)) at diamond-angle parameter p in [-2,2].
// ROUND-2 LESSON: keep this UN-unrolled with libm tanhf. The fully-unrolled
// tanh_pre version spilled (FETCH/WRITE +3.5 MB scratch) and its 8 serial
// tail blocks became a ~50 us near-idle critical path.
static __device__ float s_of_p(float pth,
    const float* __restrict__ Wp1, const float* __restrict__ bp1,
    const float* __restrict__ Wp2, const float* __restrict__ bp2,
    const float* __restrict__ Wp3, const float* __restrict__ bp3,
    const float* __restrict__ Wp4, const float* __restrict__ bp4)
{
    float th;
    if (pth >= -1.0f && pth <= 1.0f) {
        th = atanf(pth / (1.0f - fabsf(pth)));      // /0 -> inf -> atan=pi/2 ok
    } else if (pth > 1.0f) {
        const float uu = 2.0f - pth;                // [0,1)
        th = (float)M_PI - atanf(uu / (1.0f - uu));
    } else {
        const float uu = -2.0f - pth;               // (-1,0]
        th = -(float)M_PI + atanf(-uu / (1.0f + uu));
    }
    const float cth = cosf(th), sth = sinf(th);

    // phi-MLP in f32 with exact tanh: 2 -> 15 -> 15 -> 15 -> 4
    float h[15], h2[15];
    for (int j = 0; j < 15; ++j)
        h[j] = tanhf(cth * Wp1[j] + sth * Wp1[15 + j] + bp1[j]);
    for (int j = 0; j < 15; ++j) {
        float a = bp2[j];
        for (int k = 0; k < 15; ++k) a += h[k] * Wp2[k * 15 + j];
        h2[j] = tanhf(a);
    }
    for (int j = 0; j < 15; ++j) {
        float a = bp3[j];
        for (int k = 0; k < 15; ++k) a += h2[k] * Wp3[k * 15 + j];
        h[j] = tanhf(a);
    }
    float ph[4];
    for (int j = 0; j < 4; ++j) {
        float a = bp4[j];
        for (int k = 0; k < 15; ++k) a += h[k] * Wp4[k * 4 + j];
        ph[j] = a;
    }
    return ph[0] + ph[1] * sinf(0.5f * th) + ph[2] * sth + ph[3] * sinf(1.5f * th);
}

// Blocks [0, WBLK2): w(x)-grid, TWO LANES PER NODE. Round-1/2 counters showed
// the 1-thread/node version latency-bound at 1.6 blocks/CU (VALUBusy 19%,
// occupancy 8%): wave count was the binding resource. Lane pair (2g, 2g+1)
// computes node g; each lane owns half the 30-wide hidden vector (padded to
// 16, weights re-laid as [30][2][16] in LDS for aligned float4 reads), and
// layer boundaries exchange 15 floats via intra-wave __shfl_xor(.,1).
// => 2x waves, ~0.5x per-wave VALU+LDS work, ~10% shuffle overhead.
// Blocks [WBLK2, WBLK2+8): s(theta) table. Branch is BLOCK-uniform.
__global__ __launch_bounds__(256) void prep_kernel(
    const float* __restrict__ imv,
    const float* __restrict__ Ww1, const float* __restrict__ bw1,
    const float* __restrict__ Ww2, const float* __restrict__ bw2,
    const float* __restrict__ Ww3, const float* __restrict__ bw3,
    const float* __restrict__ Ww4, const float* __restrict__ bw4,
    const float* __restrict__ Wp1, const float* __restrict__ bp1,
    const float* __restrict__ Wp2, const float* __restrict__ bp2,
    const float* __restrict__ Wp3, const float* __restrict__ bp3,
    const float* __restrict__ Wp4, const float* __restrict__ bp4)
{
    const int t = threadIdx.x;

    if (blockIdx.x < WBLK2) {
        // ---- stage prescaled weights into LDS, padded-half layout ----
        // sW2p/sW3p: [k][half][16] (m==15 is a zero pad), 960 floats each.
        __shared__ float sW1[60], sb1[30], sW2p[960], sb2p[32],
                         sW3p[960], sb3p[32], sW4[240], sb4[8];
        for (int i = t; i < 960; i += 256) {
            const int k = i >> 5, r = i & 31, hf = r >> 4, m = r & 15;
            const bool pad = (m == 15);
            sW2p[i] = pad ? 0.0f : CEXP * Ww2[k * 30 + hf * 15 + m];
            sW3p[i] = pad ? 0.0f : CEXP * Ww3[k * 30 + hf * 15 + m];
        }
        if (t < 240) sW4[t] = Ww4[t];
        if (t < 60)  sW1[t] = CEXP * Ww1[t];
        if (t < 32) {
            const int hf = t >> 4, m = t & 15;
            sb2p[t] = (m < 15) ? CEXP * bw2[hf * 15 + m] : 0.0f;
            sb3p[t] = (m < 15) ? CEXP * bw3[hf * 15 + m] : 0.0f;
        }
        if (t < 30) sb1[t] = CEXP * bw1[t];
        if (t < 8)  sb4[t] = bw4[t];
        __syncthreads();

        const int gid = blockIdx.x * 128 + (t >> 1);
        if (gid >= NNODES) return;              // pair-aligned exit: shfl safe
        const int half = t & 1;                 // which 15-output half I own
        const int hb   = half * 15;
        const int ix = gid % NN, iy = gid / NN;
        const float x0 = (float)ix * (1.0f / (float)NC);
        const float x1 = (float)iy * (1.0f / (float)NC);

        // ---- layer 1: 2 -> 30, my 15 outputs ----
        float hme[15];
        #pragma unroll
        for (int m = 0; m < 15; ++m)
            hme[m] = tanh_pre(fmaf(x1, sW1[30 + hb + m],
                              fmaf(x0, sW1[hb + m], sb1[hb + m])));

        // exchange -> full 30-vector (constant indices only; half-select via
        // cndmask, no runtime array indexing)
        float hall[30];
        #pragma unroll
        for (int m = 0; m < 15; ++m) {
            const float hn = __shfl_xor(hme[m], 1);
            hall[m]      = half ? hn : hme[m];
            hall[15 + m] = half ? hme[m] : hn;
        }

        // ---- layer 2: 30 -> 30, my 16 accumulators (a[15] is junk pad) ----
        float a[16];
        #pragma unroll
        for (int m = 0; m < 16; ++m) a[m] = sb2p[half * 16 + m];
        {
            const float* Wb = &sW2p[half * 16];   // 64 B aligned
            #pragma unroll
            for (int k = 0; k < 30; ++k) {
                const float hk = hall[k];
                const float4 w0 = *(const float4*)&Wb[k * 32 + 0];
                const float4 w1 = *(const float4*)&Wb[k * 32 + 4];
                const float4 w2 = *(const float4*)&Wb[k * 32 + 8];
                const float4 w3 = *(const float4*)&Wb[k * 32 + 12];
                a[0]  = fmaf(hk, w0.x, a[0]);  a[1]  = fmaf(hk, w0.y, a[1]);
                a[2]  = fmaf(hk, w0.z, a[2]);  a[3]  = fmaf(hk, w0.w, a[3]);
                a[4]  = fmaf(hk, w1.x, a[4]);  a[5]  = fmaf(hk, w1.y, a[5]);
                a[6]  = fmaf(hk, w1.z, a[6]);  a[7]  = fmaf(hk, w1.w, a[7]);
                a[8]  = fmaf(hk, w2.x, a[8]);  a[9]  = fmaf(hk, w2.y, a[9]);
                a[10] = fmaf(hk, w2.z, a[10]); a[11] = fmaf(hk, w2.w, a[11]);
                a[12] = fmaf(hk, w3.x, a[12]); a[13] = fmaf(hk, w3.y, a[13]);
                a[14] = fmaf(hk, w3.z, a[14]); a[15] = fmaf(hk, w3.w, a[15]);
            }
        }
        #pragma unroll
        for (int m = 0; m < 15; ++m) a[m] = tanh_pre(a[m]);

        float hall2[30];
        #pragma unroll
        for (int m = 0; m < 15; ++m) {
            const float an = __shfl_xor(a[m], 1);
            hall2[m]      = half ? an : a[m];
            hall2[15 + m] = half ? a[m] : an;
        }

        // ---- layer 3: 30 -> 30 ----
        float b[16];
        #pragma unroll
        for (int m = 0; m < 16; ++m) b[m] = sb3p[half * 16 + m];
        {
            const float* Wb = &sW3p[half * 16];
            #pragma unroll
            for (int k = 0; k < 30; ++k) {
                const float hk = hall2[k];
                const float4 w0 = *(const float4*)&Wb[k * 32 + 0];
                const float4 w1 = *(const float4*)&Wb[k * 32 + 4];
                const float4 w2 = *(const float4*)&Wb[k * 32 + 8];
                const float4 w3 = *(const float4*)&Wb[k * 32 + 12];
                b[0]  = fmaf(hk, w0.x, b[0]);  b[1]  = fmaf(hk, w0.y, b[1]);
                b[2]  = fmaf(hk, w0.z, b[2]);  b[3]  = fmaf(hk, w0.w, b[3]);
                b[4]  = fmaf(hk, w1.x, b[4]);  b[5]  = fmaf(hk, w1.y, b[5]);
                b[6]  = fmaf(hk, w1.z, b[6]);  b[7]  = fmaf(hk, w1.w, b[7]);
                b[8]  = fmaf(hk, w2.x, b[8]);  b[9]  = fmaf(hk, w2.y, b[9]);
                b[10] = fmaf(hk, w2.z, b[10]); b[11] = fmaf(hk, w2.w, b[11]);
                b[12] = fmaf(hk, w3.x, b[12]); b[13] = fmaf(hk, w3.y, b[13]);
                b[14] = fmaf(hk, w3.z, b[14]); b[15] = fmaf(hk, w3.w, b[15]);
            }
        }
        #pragma unroll
        for (int m = 0; m < 15; ++m) b[m] = tanh_pre(b[m]);

        float hall3[30];
        #pragma unroll
        for (int m = 0; m < 15; ++m) {
            const float bn = __shfl_xor(b[m], 1);
            hall3[m]      = half ? bn : b[m];
            hall3[15 + m] = half ? b[m] : bn;
        }

        // ---- layer 4: 30 -> 8, my 4 outputs (half0: o0..3, half1: o4..7) ----
        float o[4];
        #pragma unroll
        for (int q = 0; q < 4; ++q) o[q] = sb4[half * 4 + q];
        {
            const float* Wb = &sW4[half * 4];     // 16 B aligned
            #pragma unroll
            for (int k = 0; k < 30; ++k) {
                const float hk = hall3[k];
                const float4 w = *(const float4*)&Wb[k * 8];
                o[0] = fmaf(hk, w.x, o[0]); o[1] = fmaf(hk, w.y, o[1]);
                o[2] = fmaf(hk, w.z, o[2]); o[3] = fmaf(hk, w.w, o[3]);
            }
        }
        float on0 = __shfl_xor(o[0], 1), on1 = __shfl_xor(o[1], 1);
        float on2 = __shfl_xor(o[2], 1), on3 = __shfl_xor(o[3], 1);

        if (half == 0) {
            // fold yita(node): c_j = w_j + y * w_{4+j}
            const float ddx = x0 - imv[0], ddy = x1 - imv[1];
            const float rr  = sqrtf(fmaf(ddx, ddx, ddy * ddy));
            const float tt  = fminf(fmaxf(fmaf(2.5f, rr, -1.25f), 0.0f), 1.0f);
            const float tt3 = tt * tt * tt;
            const float yv  = fmaf(fmaf(fmaf(-6.0f, tt, 15.0f), tt, -10.0f), tt3, 1.0f);
            float4 v;
            v.x = fmaf(yv, on0, o[0]);
            v.y = fmaf(yv, on1, o[1]);
            v.z = fmaf(yv, on2, o[2]);
            v.w = fmaf(yv, on3, o[3]);
            g_ctab[gid] = v;
        }
        return;
    }

    // ---- s(theta) table blocks ----
    const int cell = (blockIdx.x - WBLK2) * 256 + t;
    if (cell < TABN) {
        const float hh = 4.0f / (float)TABN;
        const float p0 = -2.0f + hh * (float)cell;
        const float s0 = s_of_p(p0,      Wp1, bp1, Wp2, bp2, Wp3, bp3, Wp4, bp4);
        const float s1 = s_of_p(p0 + hh, Wp1, bp1, Wp2, bp2, Wp3, bp3, Wp4, bp4);
        float2 e; e.x = s0; e.y = s1 - s0;
        g_stab2[cell] = e;
    }
}

// 2 points per thread. Per point: one bilinear gather of the 4 folded coeffs
// (4x dwordx4), one 8 B s(theta) gather, ~70 VALU ops of closed-form geometry.
__global__ __launch_bounds__(256) void interior_kernel(
    const float4* __restrict__ x,      // two points per float4
    const float*  __restrict__ imv,
    const float*  __restrict__ lmbd,
    float* __restrict__ out, int n2)   // n2 = n/2
{
    const int idx = blockIdx.x * blockDim.x + threadIdx.x;
    if (idx >= n2) return;

    const float4 xx = x[idx];
    const float X0[2] = {xx.x, xx.z};
    const float X1[2] = {xx.y, xx.w};
    const float im0 = imv[0], im1 = imv[1], lam = lmbd[0];

    const float4* __restrict__ T = g_ctab;

    float res[2];
    #pragma unroll
    for (int p = 0; p < 2; ++p) {
        const float x0 = X0[p], x1 = X1[p];

        // ---- bilinear gather of folded coeffs c[0..4) from the 2-D grid ----
        const float fx = x0 * (float)NC;
        const float fy = x1 * (float)NC;
        int ix = (int)fx; ix = ix < 0 ? 0 : (ix > NC - 1 ? NC - 1 : ix);
        int iy = (int)fy; iy = iy < 0 ? 0 : (iy > NC - 1 ? NC - 1 : iy);
        const float frx = fx - (float)ix;
        const float fry = fy - (float)iy;

        const int k = iy * NN + ix;              // float4 units
        const float4 A = T[k],      B = T[k + 1];        // (ix,iy) (ix+1,iy)
        const float4 Cq = T[k + NN], D = T[k + NN + 1];  // row iy+1

        float cv[4];
        {
            const float r0x = fmaf(frx, B.x - A.x, A.x);
            const float r0y = fmaf(frx, B.y - A.y, A.y);
            const float r0z = fmaf(frx, B.z - A.z, A.z);
            const float r0w = fmaf(frx, B.w - A.w, A.w);
            const float r1x = fmaf(frx, D.x - Cq.x, Cq.x);
            const float r1y = fmaf(frx, D.y - Cq.y, Cq.y);
            const float r1z = fmaf(frx, D.z - Cq.z, Cq.z);
            const float r1w = fmaf(frx, D.w - Cq.w, Cq.w);
            cv[0] = fmaf(fry, r1x - r0x, r0x);
            cv[1] = fmaf(fry, r1y - r0y, r0y);
            cv[2] = fmaf(fry, r1z - r0z, r0z);
            cv[3] = fmaf(fry, r1w - r0w, r0w);
        }

        // ---- geometry about the interior vertex ----
        const float dx = x0 - im0, dy = x1 - im1;
        const float r  = sqrtf(fmaf(dx, dx, dy * dy));

        // yita(r) -- exact, still needed for the sp term
        const float t  = fminf(fmaxf(fmaf(2.5f, r, -1.25f), 0.0f), 1.0f);
        const float t3 = t * t * t;
        const float yv = fmaf(fmaf(fmaf(-6.0f, t, 15.0f), t, -10.0f), t3, 1.0f);

        // r^lambda (sqrt fast path for lambda == 0.5)
        float rl;
        if (lam == 0.5f) rl = sqrtf(r);
        else rl = __builtin_amdgcn_exp2f(lam * __builtin_amdgcn_logf(fmaxf(r, 1e-20f)));

        // diamond-angle parameter p(theta) in [-2,2], no trig
        const float l1n = fmaxf(fabsf(dx) + fabsf(dy), 1e-20f);
        const float u   = dy * __builtin_amdgcn_rcpf(l1n);
        const float pbk = (dy >= 0.0f) ? (2.0f - u) : (-2.0f - u);
        const float pth = (dx >= 0.0f) ? u : pbk;

        // s(theta) table gather: cell {s, ds}, one 8 B load
        const float fi = fminf(fmaxf(fmaf(pth, (float)(TABN / 4), (float)(TABN / 2)),
                                     0.0f), (float)TABN - 0.001f);
        const int   ii = (int)fi;
        const float fr = fi - (float)ii;
        const float2 sd = g_stab2[ii];
        const float sval = fmaf(fr, sd.y, sd.x);

        // singular functions at x (about origin), algebraically reduced:
        // vp0 = r0^0.5 sin(th/2) = copysign(sqrt((r0-x0)/2), x1)
        // vp1 = x1
        // vp2 = r0^1.5 sin(1.5 th) = x1*sqrt((r0+x0)/2) + x0*vp0
        const float r0 = sqrtf(fmaf(x0, x0, x1 * x1));
        const float Aq = sqrtf(fmaxf(0.0f, (r0 - x0) * 0.5f));
        const float Bq = sqrtf(fmaxf(0.0f, (r0 + x0) * 0.5f));
        const float vp0 = copysignf(Aq, x1);
        const float vp2 = fmaf(x1, Bq, x0 * vp0);

        // combine (yita already folded into cv[])
        float rp = cv[0];
        rp = fmaf(cv[1], vp0, rp);
        rp = fmaf(cv[2], x1, rp);
        rp = fmaf(cv[3], vp2, rp);
        res[p] = fmaf(sval * yv, rl, rp);
    }

    float2 o; o.x = res[0]; o.y = res[1];
    ((float2*)out)[idx] = o;
}

extern "C" void kernel_launch(void* const* d_in, const int* in_sizes, int n_in,
                              void* d_out, int out_size, void* d_ws, size_t ws_size,
                              hipStream_t stream) {
    const float4* x   = (const float4*)d_in[0];
    const float* imv  = (const float*)d_in[1];
    const float* lmbd = (const float*)d_in[2];
    const float* Ww1  = (const float*)d_in[3];
    const float* bw1  = (const float*)d_in[4];
    const float* Ww2  = (const float*)d_in[5];
    const float* bw2  = (const float*)d_in[6];
    const float* Ww3  = (const float*)d_in[7];
    const float* bw3  = (const float*)d_in[8];
    const float* Ww4  = (const float*)d_in[9];
    const float* bw4  = (const float*)d_in[10];
    const float* Wp1  = (const float*)d_in[11];
    const float* bp1  = (const float*)d_in[12];
    const float* Wp2  = (const float*)d_in[13];
    const float* bp2  = (const float*)d_in[14];
    const float* Wp3  = (const float*)d_in[15];
    const float* bp3  = (const float*)d_in[16];
    const float* Wp4  = (const float*)d_in[17];
    const float* bp4  = (const float*)d_in[18];
    float* out = (float*)d_out;

    const int n  = in_sizes[0] / 2;
    const int n2 = n / 2;

    // WBLK2 blocks for the w-grid (2 lanes/node) + 8 blocks for the s-table.
    prep_kernel<<<WBLK2 + (TABN + 255) / 256, 256, 0, stream>>>(
        imv,
        Ww1, bw1, Ww2, bw2, Ww3, bw3, Ww4, bw4,
        Wp1, bp1, Wp2, bp2, Wp3, bp3, Wp4, bp4);

    const int block = 256;
    const int grid = (n2 + block - 1) / block;
    interior_kernel<<<grid, block, 0, stream>>>(x, imv, lmbd, out, n2);
}